// Round 1
// baseline (438.866 us; speedup 1.0000x reference)
//
#include <hip/hip_runtime.h>

#define Bn   16
#define Cn   512
#define Hn   80
#define Wn   80
#define HWn  (Hn*Wn)          // 6400
#define CHWn (Cn*HWn)         // 3276800
#define TOTALn (Bn*CHWn)      // 52428800
#define NMAX (Bn*HWn)         // 102400

#define K2_BLOCK 256
#define K2_ITERS 16
#define ELEMS_PER_BLOCK (K2_BLOCK*K2_ITERS)   // 4096
#define NBLK (TOTALn/ELEMS_PER_BLOCK)         // 12800
#define NWORDS (TOTALn/64)                    // 819200

// ---------------- K0: fill output with pad values ----------------
// grid_keypoints pad = -1 ; keypoints pad = upscale(-1) = -1*8+3.5 = -4.5
__global__ void k_fill(float* __restrict__ out) {
    int i = blockIdx.x * 256 + threadIdx.x;          // 0 .. 4*NMAX-1 (409600)
    out[i] = (i < 2 * NMAX) ? -1.0f : -4.5f;
}

// ---------------- K1: depth-wise max per pixel ----------------
// block = 256 threads = 64 pixels x 4 channel-groups of 128.
__global__ void k_dmax(const float* __restrict__ in, float* __restrict__ dmax) {
    int t    = threadIdx.x;
    int pixL = t & 63;
    int cg   = t >> 6;                                // 0..3
    int pix  = blockIdx.x * 64 + pixL;                // 0..102399
    int b    = pix / HWn;
    int hw   = pix % HWn;
    const float* base = in + (size_t)b * CHWn + (size_t)(cg * 128) * HWn + hw;
    float m0 = -INFINITY, m1 = -INFINITY;
    #pragma unroll 4
    for (int c = 0; c < 128; c += 2) {
        m0 = fmaxf(m0, base[(size_t)c * HWn]);
        m1 = fmaxf(m1, base[(size_t)(c + 1) * HWn]);
    }
    __shared__ float s[4][64];
    s[cg][pixL] = fmaxf(m0, m1);
    __syncthreads();
    if (t < 64) {
        float r = fmaxf(fmaxf(s[0][pixL], s[1][pixL]), fmaxf(s[2][pixL], s[3][pixL]));
        dmax[pix] = fmaxf(r, 0.0f);                   // relu(max) == max(relu)
    }
}

// ---------------- K2: detection bitmask + per-block counts ----------------
__global__ void k_detect(const float* __restrict__ in, const float* __restrict__ dmax,
                         unsigned long long* __restrict__ mask,
                         unsigned int* __restrict__ counts) {
    const int t    = threadIdx.x;
    const int blk  = blockIdx.x;
    const int wave = t >> 6, lane = t & 63;
    const int baseFlat = blk * ELEMS_PER_BLOCK;
    int myCount = 0;
    for (int it = 0; it < K2_ITERS; ++it) {
        int flat = baseFlat + it * 256 + t;
        float v = in[flat];
        float x = fmaxf(v, 0.0f);
        unsigned int uf = (unsigned int)flat;
        int hw  = (int)(uf % HWn);
        int pix = (int)(uf / CHWn) * HWn + hw;
        bool det = false;
        if (x == dmax[pix]) {
            int h = hw / Wn, w = hw % Wn;
            const float* pl = in + flat;
            bool ok = true;
            if (w > 0)      ok &= (x >= pl[-1]);
            if (w < Wn - 1) ok &= (x >= pl[1]);
            if (h > 0) {
                const float* q = pl - Wn;
                ok &= (x >= q[0]);
                if (w > 0)      ok &= (x >= q[-1]);
                if (w < Wn - 1) ok &= (x >= q[1]);
            }
            if (h < Hn - 1) {
                const float* q = pl + Wn;
                ok &= (x >= q[0]);
                if (w > 0)      ok &= (x >= q[-1]);
                if (w < Wn - 1) ok &= (x >= q[1]);
            }
            det = ok;
        }
        unsigned long long ball = __ballot(det);
        if (lane == 0) mask[blk * 64 + it * 4 + wave] = ball;
        myCount += (int)__popcll(ball);
    }
    __shared__ int s[4];
    if (lane == 0) s[wave] = myCount;
    __syncthreads();
    if (t == 0) counts[blk] = (unsigned int)(s[0] + s[1] + s[2] + s[3]);
}

// ---------------- K3: exclusive scan of 12800 block counts (1 block) ----------------
__global__ void k_scan(const unsigned int* __restrict__ counts,
                       unsigned int* __restrict__ offsets) {
    __shared__ unsigned int s[256];
    __shared__ unsigned int carry;
    int t = threadIdx.x;
    if (t == 0) carry = 0;
    __syncthreads();
    for (int chunk = 0; chunk < NBLK; chunk += 256) {
        unsigned int v = counts[chunk + t];
        s[t] = v;
        __syncthreads();
        for (int off = 1; off < 256; off <<= 1) {
            unsigned int add = (t >= off) ? s[t - off] : 0u;
            __syncthreads();
            s[t] += add;
            __syncthreads();
        }
        offsets[chunk + t] = carry + s[t] - v;    // exclusive
        __syncthreads();
        if (t == 255) carry += s[255];
        __syncthreads();
    }
}

// ---------------- K4: emit compacted keypoints from bitmask ----------------
__global__ void k_emit(const unsigned long long* __restrict__ mask,
                       const unsigned int* __restrict__ offsets,
                       float* __restrict__ out) {
    int blk  = blockIdx.x;
    int lane = threadIdx.x;                        // 64 threads
    unsigned long long wd = mask[blk * 64 + lane];
    int cnt = (int)__popcll(wd);
    int pre = cnt;
    #pragma unroll
    for (int off = 1; off < 64; off <<= 1) {
        int n = __shfl_up(pre, off);
        if (lane >= off) pre += n;
    }
    unsigned int outIdx = offsets[blk] + (unsigned int)(pre - cnt);
    int wordFlatBase = (blk * 64 + lane) * 64;
    while (wd) {
        int bit = __builtin_ctzll(wd);
        wd &= wd - 1;
        unsigned int flat = (unsigned int)(wordFlatBase + bit);
        int hw = (int)(flat % HWn);
        int h = hw / Wn, w = hw % Wn;
        if (outIdx < NMAX) {
            out[2 * outIdx]     = (float)h;
            out[2 * outIdx + 1] = (float)w;
            out[2 * NMAX + 2 * outIdx]     = 8.0f * (float)h + 3.5f;
            out[2 * NMAX + 2 * outIdx + 1] = 8.0f * (float)w + 3.5f;
        }
        ++outIdx;
    }
}

extern "C" void kernel_launch(void* const* d_in, const int* in_sizes, int n_in,
                              void* d_out, int out_size, void* d_ws, size_t ws_size,
                              hipStream_t stream) {
    const float* in = (const float*)d_in[0];
    float* out = (float*)d_out;

    char* ws = (char*)d_ws;
    float*              dmax    = (float*)ws;                          // 409600 B
    unsigned long long* mask    = (unsigned long long*)(ws + 409600);  // 6553600 B
    unsigned int*       counts  = (unsigned int*)(ws + 409600 + 6553600);         // 51200 B
    unsigned int*       offsets = (unsigned int*)(ws + 409600 + 6553600 + 51200); // 51200 B

    k_fill<<<(4 * NMAX) / 256, 256, 0, stream>>>(out);
    k_dmax<<<NMAX / 64, 256, 0, stream>>>(in, dmax);
    k_detect<<<NBLK, K2_BLOCK, 0, stream>>>(in, dmax, mask, counts);
    k_scan<<<1, 256, 0, stream>>>(counts, offsets);
    k_emit<<<NBLK, 64, 0, stream>>>(mask, offsets, out);
}

// Round 2
// 350.954 us; speedup vs baseline: 1.2505x; 1.2505x over previous
//
#include <hip/hip_runtime.h>

#define Bn   16
#define Cn   512
#define Hn   80
#define Wn   80
#define HWn  (Hn*Wn)          // 6400
#define CHWn (Cn*HWn)         // 3276800
#define TOTALn (Bn*CHWn)      // 52428800
#define NMAX (Bn*HWn)         // 102400
#define NWORDS (TOTALn/64)    // 819200 u64 words in detection bitmask
#define NRANGE (NWORDS/64)    // 12800 ranges (4096 elements each) for scan/emit

#define PIX 128               // pixels per fused block
#define NCHUNK (HWn/PIX)      // 50
#define GRID_A (Bn*NCHUNK)    // 800

// ---------------- K0: fill output with pad values ----------------
// grid_keypoints pad = -1 ; keypoints pad = -1*8+3.5 = -4.5
__global__ void k_fill(float* __restrict__ out) {
    int i = blockIdx.x * 256 + threadIdx.x;          // 0 .. 409599
    out[i] = (i < 2 * NMAX) ? -1.0f : -4.5f;
}

// ---------------- K1: fused depthwise-max + detection bitmask ----------------
// Block = 256 threads (4 waves). Block owns (b, hw chunk of 128 pixels, ALL 512 ch).
// Wave w streams channels [w*128, w*128+128); lane covers 2 pixels via float2.
// Tracks running max + 128-bit tie mask per pixel; merge in LDS; test 3x3 local
// max only for candidate elements (x == dmax), set bits in LDS word image,
// write the block's 1024 mask words (c-major) to global.
__global__ __launch_bounds__(256) void k_fused(const float* __restrict__ in,
                                               unsigned long long* __restrict__ mask) {
    __shared__ float s_max[4][PIX];
    __shared__ unsigned long long s_lo[4][PIX];
    __shared__ unsigned long long s_hi[4][PIX];
    __shared__ unsigned int s_out[Cn * (PIX / 32)];   // 2048 u32 = 8 KB

    const int t = threadIdx.x, wave = t >> 6, lane = t & 63;
    const int b = blockIdx.x / NCHUNK, chunk = blockIdx.x % NCHUNK;
    const int hwBase = chunk * PIX;

    for (int i = t; i < Cn * (PIX / 32); i += 256) s_out[i] = 0u;

    const float* base = in + (size_t)b * CHWn + (size_t)(wave * 128) * HWn
                          + hwBase + lane * 2;
    float m0 = -INFINITY, m1 = -INFINITY;
    unsigned long long lo0 = 0, lo1 = 0, hi0 = 0, hi1 = 0;
    #pragma unroll 8
    for (int c = 0; c < 64; ++c) {
        float2 v = *(const float2*)(base + (size_t)c * HWn);
        unsigned long long bit = 1ull << c;
        if (v.x > m0)       { m0 = v.x; lo0 = bit; }
        else if (v.x == m0) { lo0 |= bit; }
        if (v.y > m1)       { m1 = v.y; lo1 = bit; }
        else if (v.y == m1) { lo1 |= bit; }
    }
    #pragma unroll 8
    for (int c = 0; c < 64; ++c) {
        float2 v = *(const float2*)(base + (size_t)(64 + c) * HWn);
        unsigned long long bit = 1ull << c;
        if (v.x > m0)       { m0 = v.x; lo0 = 0; hi0 = bit; }
        else if (v.x == m0) { hi0 |= bit; }
        if (v.y > m1)       { m1 = v.y; lo1 = 0; hi1 = bit; }
        else if (v.y == m1) { hi1 |= bit; }
    }
    int p0 = lane * 2, p1 = lane * 2 + 1;
    s_max[wave][p0] = m0; s_lo[wave][p0] = lo0; s_hi[wave][p0] = hi0;
    s_max[wave][p1] = m1; s_lo[wave][p1] = lo1; s_hi[wave][p1] = hi1;
    __syncthreads();

    if (t < PIX) {
        const int p = t;
        float fm = fmaxf(fmaxf(s_max[0][p], s_max[1][p]),
                         fmaxf(s_max[2][p], s_max[3][p]));
        float x = fmaxf(fm, 0.0f);                    // relu(max) == max(relu)
        int hw = hwBase + p, h = hw / Wn, w = hw % Wn;
        const float* ibase = in + (size_t)b * CHWn + hw;

        unsigned long long cand[8];
        #pragma unroll
        for (int g = 0; g < 4; ++g) {
            bool sel = (s_max[g][p] == fm);
            cand[2 * g]     = sel ? s_lo[g][p] : 0ull;
            cand[2 * g + 1] = sel ? s_hi[g][p] : 0ull;
        }
        if (fm <= 0.0f) {                             // dmax==0: every channel ties
            #pragma unroll
            for (int g = 0; g < 8; ++g) cand[g] = ~0ull;
        }
        #pragma unroll
        for (int g = 0; g < 8; ++g) {
            unsigned long long wd = cand[g];
            while (wd) {
                int bit = __builtin_ctzll(wd);
                wd &= wd - 1;
                int c = g * 64 + bit;
                const float* pl = ibase + (size_t)c * HWn;
                bool ok = true;                       // x>=0 so x>=relu(n) <=> x>=n
                if (w > 0)      ok &= (x >= pl[-1]);
                if (w < Wn - 1) ok &= (x >= pl[1]);
                if (h > 0) {
                    const float* q = pl - Wn;
                    ok &= (x >= q[0]);
                    if (w > 0)      ok &= (x >= q[-1]);
                    if (w < Wn - 1) ok &= (x >= q[1]);
                }
                if (h < Hn - 1) {
                    const float* q = pl + Wn;
                    ok &= (x >= q[0]);
                    if (w > 0)      ok &= (x >= q[-1]);
                    if (w < Wn - 1) ok &= (x >= q[1]);
                }
                if (ok) atomicOr(&s_out[c * (PIX / 32) + (p >> 5)], 1u << (p & 31));
            }
        }
    }
    __syncthreads();

    // write 1024 u64 words (as 2048 u32): per channel c, 2 u64 at global word
    // (b*512+c)*100 + chunk*2  (u32 index = that*2, 16B-aligned)
    unsigned int* gmask32 = (unsigned int*)mask;
    for (int cc = t; cc < Cn; cc += 256) {
        uint4 vv = *(const uint4*)&s_out[cc * 4];
        size_t gi = ((size_t)(b * Cn + cc) * 100 + chunk * 2) * 2;
        *(uint4*)&gmask32[gi] = vv;
    }
}

// ---------------- K2: per-range popcounts (range = 64 words = 4096 elems) ----
__global__ void k_count(const unsigned long long* __restrict__ mask,
                        unsigned int* __restrict__ counts) {
    int wave = threadIdx.x >> 6, lane = threadIdx.x & 63;
    int range = blockIdx.x * 4 + wave;                // grid = NRANGE/4
    int c = (int)__popcll(mask[range * 64 + lane]);
    #pragma unroll
    for (int off = 1; off < 64; off <<= 1) c += __shfl_xor(c, off);
    if (lane == 0) counts[range] = (unsigned int)c;
}

// ---------------- K3: exclusive scan of 12800 counts (1 block, 2-pass) -------
__global__ __launch_bounds__(256) void k_scan(const unsigned int* __restrict__ counts,
                                              unsigned int* __restrict__ offsets) {
    __shared__ unsigned int s[256];
    const int t = threadIdx.x;
    const int PER = NRANGE / 256;                     // 50
    unsigned int sum = 0;
    for (int i = 0; i < PER; ++i) sum += counts[t * PER + i];
    s[t] = sum;
    __syncthreads();
    for (int off = 1; off < 256; off <<= 1) {
        unsigned int add = (t >= off) ? s[t - off] : 0u;
        __syncthreads();
        s[t] += add;
        __syncthreads();
    }
    unsigned int run = s[t] - sum;                    // exclusive base
    for (int i = 0; i < PER; ++i) {
        unsigned int v = counts[t * PER + i];
        offsets[t * PER + i] = run;
        run += v;
    }
}

// ---------------- K4: emit compacted keypoints from bitmask ------------------
__global__ void k_emit(const unsigned long long* __restrict__ mask,
                       const unsigned int* __restrict__ offsets,
                       float* __restrict__ out) {
    int range = blockIdx.x;
    int lane  = threadIdx.x;                          // 64 threads
    unsigned long long wd = mask[range * 64 + lane];
    int cnt = (int)__popcll(wd);
    int pre = cnt;
    #pragma unroll
    for (int off = 1; off < 64; off <<= 1) {
        int n = __shfl_up(pre, off);
        if (lane >= off) pre += n;
    }
    unsigned int outIdx = offsets[range] + (unsigned int)(pre - cnt);
    unsigned int wordFlatBase = (unsigned int)(range * 64 + lane) * 64u;
    while (wd) {
        int bit = __builtin_ctzll(wd);
        wd &= wd - 1;
        unsigned int flat = wordFlatBase + (unsigned int)bit;
        int hw = (int)(flat % HWn);
        int h = hw / Wn, w = hw % Wn;
        if (outIdx < NMAX) {
            out[2 * outIdx]     = (float)h;
            out[2 * outIdx + 1] = (float)w;
            out[2 * NMAX + 2 * outIdx]     = 8.0f * (float)h + 3.5f;
            out[2 * NMAX + 2 * outIdx + 1] = 8.0f * (float)w + 3.5f;
        }
        ++outIdx;
    }
}

extern "C" void kernel_launch(void* const* d_in, const int* in_sizes, int n_in,
                              void* d_out, int out_size, void* d_ws, size_t ws_size,
                              hipStream_t stream) {
    const float* in = (const float*)d_in[0];
    float* out = (float*)d_out;

    char* ws = (char*)d_ws;
    unsigned long long* mask    = (unsigned long long*)ws;                    // 6,553,600 B
    unsigned int*       counts  = (unsigned int*)(ws + 6553600);              // 51,200 B
    unsigned int*       offsets = (unsigned int*)(ws + 6553600 + 51200);      // 51,200 B

    k_fill<<<(4 * NMAX) / 256, 256, 0, stream>>>(out);
    k_fused<<<GRID_A, 256, 0, stream>>>(in, mask);
    k_count<<<NRANGE / 4, 256, 0, stream>>>(mask, counts);
    k_scan<<<1, 256, 0, stream>>>(counts, offsets);
    k_emit<<<NRANGE, 64, 0, stream>>>(mask, offsets, out);
}